// Round 5
// baseline (1089.695 us; speedup 1.0000x reference)
//
#include <hip/hip_runtime.h>
#include <cmath>

#define DD 128          // embedding dim
#define NEGS 256        // negatives per anchor
#define LTILE 64        // rows per linear block

// ---------------------------------------------------------------------------
// init: zero loss accumulator + histogram + scatter cursors
// ---------------------------------------------------------------------------
__global__ __launch_bounds__(256) void init_kernel(double* accum, int* hist,
                                                   int* cursor, int n) {
    int i = blockIdx.x * 256 + threadIdx.x;
    if (i == 0) accum[0] = 0.0;
    if (i < n) { hist[i] = 0; cursor[i] = 0; }
}

// ---------------------------------------------------------------------------
// Wt[k][c] = W[c][k]
// ---------------------------------------------------------------------------
__global__ __launch_bounds__(256) void transpose_W(const float* __restrict__ W,
                                                   float* __restrict__ Wt) {
    int e = blockIdx.x * 256 + threadIdx.x;
    int c = e >> 7;
    int k = e & 127;
    Wt[k * DD + c] = W[e];
}

// ---------------------------------------------------------------------------
// emb = X @ W.T + b  (fp32 vector ALU).
// 256 thr: cg = t&15 -> 8 cols, rg = t>>4 -> 4 rows. Tile 64 rows.
// X tile in padded LDS (stride 132 floats -> b128 reads conflict-free).
// W loads batched 8-wide per k-chunk for latency hiding.
// ---------------------------------------------------------------------------
__global__ __launch_bounds__(256) void linear_kernel(const float* __restrict__ X,
                                                     const float* __restrict__ Wt,
                                                     const float* __restrict__ b,
                                                     float* __restrict__ Y,
                                                     int N) {
    __shared__ __align__(16) float xs[LTILE][132];   // +4 pad: rows 528 B apart

    const int t  = threadIdx.x;
    const int cg = t & 15;   // cols cg*8 .. cg*8+7
    const int rg = t >> 4;   // rows rg*4 .. rg*4+3
    const int r0 = blockIdx.x * LTILE;

    // stage X tile (coalesced float4 in, padded rows out)
    const float4* X4 = (const float4*)X;
    #pragma unroll
    for (int i = 0; i < 8; ++i) {
        int q   = i * 256 + t;            // 0..2047
        int row = q >> 5;
        int c4  = q & 31;
        float4 v = make_float4(0.f, 0.f, 0.f, 0.f);
        if (r0 + row < N) v = X4[(size_t)(r0 + row) * 32 + c4];
        *((float4*)&xs[row][c4 * 4]) = v;
    }

    const float4* b4 = (const float4*)b;
    float4 b0 = b4[cg * 2], b1 = b4[cg * 2 + 1];
    float acc[4][8];
    #pragma unroll
    for (int j = 0; j < 4; ++j) {
        acc[j][0] = b0.x; acc[j][1] = b0.y; acc[j][2] = b0.z; acc[j][3] = b0.w;
        acc[j][4] = b1.x; acc[j][5] = b1.y; acc[j][6] = b1.z; acc[j][7] = b1.w;
    }
    __syncthreads();

    const float4* Wt4 = (const float4*)Wt;
    #pragma unroll 2
    for (int kc = 0; kc < DD / 4; ++kc) {
        float4 xv[4];
        #pragma unroll
        for (int j = 0; j < 4; ++j)
            xv[j] = *((const float4*)&xs[rg * 4 + j][kc * 4]);
        float4 w0[4], w1[4];
        #pragma unroll
        for (int kk = 0; kk < 4; ++kk) {
            w0[kk] = Wt4[(size_t)(kc * 4 + kk) * 32 + cg * 2];
            w1[kk] = Wt4[(size_t)(kc * 4 + kk) * 32 + cg * 2 + 1];
        }
        #pragma unroll
        for (int kk = 0; kk < 4; ++kk) {
            #pragma unroll
            for (int j = 0; j < 4; ++j) {
                float xk = (kk == 0) ? xv[j].x : (kk == 1) ? xv[j].y
                         : (kk == 2) ? xv[j].z : xv[j].w;
                acc[j][0] += xk * w0[kk].x;
                acc[j][1] += xk * w0[kk].y;
                acc[j][2] += xk * w0[kk].z;
                acc[j][3] += xk * w0[kk].w;
                acc[j][4] += xk * w1[kk].x;
                acc[j][5] += xk * w1[kk].y;
                acc[j][6] += xk * w1[kk].z;
                acc[j][7] += xk * w1[kk].w;
            }
        }
    }

    float4* Y4 = (float4*)Y;
    #pragma unroll
    for (int j = 0; j < 4; ++j) {
        int row = r0 + rg * 4 + j;
        if (row < N) {
            Y4[(size_t)row * 32 + cg * 2]     = make_float4(acc[j][0], acc[j][1], acc[j][2], acc[j][3]);
            Y4[(size_t)row * 32 + cg * 2 + 1] = make_float4(acc[j][4], acc[j][5], acc[j][6], acc[j][7]);
        }
    }
}

// ---------------------------------------------------------------------------
// Q[m] = emb[anchor[m]]  for m in [0, 2P): branch 0 then branch 1.
// 8 lanes per row; lane j holds float4 slots {j, 8+j, 16+j, 24+j}.
// ---------------------------------------------------------------------------
__global__ __launch_bounds__(256) void build_q(const float* __restrict__ emb,
                                               const int* __restrict__ a0,
                                               const int* __restrict__ a1,
                                               float* __restrict__ Q, int P) {
    int t = threadIdx.x;
    int g = t >> 3;
    int j = t & 7;
    int m = blockIdx.x * 32 + g;
    if (m >= 2 * P) return;
    int br = (m >= P) ? 1 : 0;
    int p  = m - br * P;
    int a  = br ? a1[p] : a0[p];
    const float4* e4 = (const float4*)emb;
    float4*       Q4 = (float4*)Q;
    #pragma unroll
    for (int i = 0; i < 4; ++i)
        Q4[(size_t)m * 32 + i * 8 + j] = e4[(size_t)a * 32 + i * 8 + j];
}

// ---------------------------------------------------------------------------
// Occurrence enumeration: idx in [0, 2*P*257). Per branch: first P*256 are
// negatives (p = k>>8, n = k&255), last P are positives (partner rows).
// ---------------------------------------------------------------------------
__global__ __launch_bounds__(256) void hist_kernel(const int* __restrict__ n0,
                                                   const int* __restrict__ pt0,
                                                   const int* __restrict__ n1,
                                                   const int* __restrict__ pt1,
                                                   int* __restrict__ hist, int P) {
    int T1  = P * 257;
    int idx = blockIdx.x * 256 + threadIdx.x;
    if (idx >= 2 * T1) return;
    int br = (idx >= T1) ? 1 : 0;
    int k  = idx - br * T1;
    int PN = P * NEGS;
    int r;
    if (k < PN) r = (br ? n1 : n0)[k];
    else        r = (br ? pt1 : pt0)[k - PN];
    atomicAdd(&hist[r], 1);
}

// ---------------------------------------------------------------------------
// 3-phase exclusive scan of hist[0..n) -> base[0..n)
// ---------------------------------------------------------------------------
__global__ __launch_bounds__(256) void scan1(const int* __restrict__ hist,
                                             int* __restrict__ bsum, int n) {
    __shared__ int s[256];
    int t = threadIdx.x;
    int i = blockIdx.x * 256 + t;
    s[t] = (i < n) ? hist[i] : 0;
    __syncthreads();
    #pragma unroll
    for (int st = 128; st >= 1; st >>= 1) {
        if (t < st) s[t] += s[t + st];
        __syncthreads();
    }
    if (t == 0) bsum[blockIdx.x] = s[0];
}

__global__ void scan2(const int* __restrict__ bsum, int* __restrict__ bofs, int nb) {
    if (threadIdx.x == 0 && blockIdx.x == 0) {
        int acc = 0;
        for (int i = 0; i < nb; ++i) { bofs[i] = acc; acc += bsum[i]; }
    }
}

__global__ __launch_bounds__(256) void scan3(const int* __restrict__ hist,
                                             const int* __restrict__ bofs,
                                             int* __restrict__ base, int n) {
    __shared__ int s[256];
    int t = threadIdx.x;
    int i = blockIdx.x * 256 + t;
    int v = (i < n) ? hist[i] : 0;
    s[t] = v;
    __syncthreads();
    for (int st = 1; st < 256; st <<= 1) {
        int add = (t >= st) ? s[t - st] : 0;
        __syncthreads();
        s[t] += add;
        __syncthreads();
    }
    if (i < n) base[i] = bofs[blockIdx.x] + s[t] - v;   // exclusive
}

// ---------------------------------------------------------------------------
// scatter occurrence records sorted by row.
// rec = br<<31 | isPos<<30 | p<<8 | n
// ---------------------------------------------------------------------------
__global__ __launch_bounds__(256) void scatter_kernel(const int* __restrict__ n0,
                                                      const int* __restrict__ pt0,
                                                      const int* __restrict__ n1,
                                                      const int* __restrict__ pt1,
                                                      const int* __restrict__ base,
                                                      int* __restrict__ cursor,
                                                      unsigned* __restrict__ list,
                                                      int P) {
    int T1  = P * 257;
    int idx = blockIdx.x * 256 + threadIdx.x;
    if (idx >= 2 * T1) return;
    int br = (idx >= T1) ? 1 : 0;
    int k  = idx - br * T1;
    int PN = P * NEGS;
    int r;
    unsigned rec;
    if (k < PN) {
        int p = k >> 8, n = k & 255;
        r   = (br ? n1 : n0)[k];
        rec = ((unsigned)br << 31) | ((unsigned)p << 8) | (unsigned)n;
    } else {
        int p = k - PN;
        r   = (br ? pt1 : pt0)[p];
        rec = ((unsigned)br << 31) | (1u << 30) | ((unsigned)p << 8);
    }
    int slot = base[r] + atomicAdd(&cursor[r], 1);
    list[slot] = rec;
}

// ---------------------------------------------------------------------------
// Main pass: one wave per emb row (rows in order -> emb streamed).
// 8 lane-groups process 8 occurrences at a time; the random gather is from
// the 8.4 MB compacted Q table (L2/L3-resident).
// ---------------------------------------------------------------------------
__global__ __launch_bounds__(256) void gather_dot(const float* __restrict__ emb,
                                                  const float* __restrict__ Q,
                                                  const unsigned* __restrict__ list,
                                                  const int* __restrict__ hist,
                                                  const int* __restrict__ base,
                                                  float* __restrict__ zbuf,
                                                  float* __restrict__ lpos,
                                                  int nrows, int P) {
    const int wv   = threadIdx.x >> 6;
    const int lane = threadIdx.x & 63;
    const int g    = lane >> 3;
    const int j    = lane & 7;
    const int r    = blockIdx.x * 4 + wv;
    if (r >= nrows) return;
    const int cnt = hist[r];
    if (cnt == 0) return;
    const int bs = base[r];

    const float4* e4 = (const float4*)emb;
    float4 er[4];
    #pragma unroll
    for (int i = 0; i < 4; ++i) er[i] = e4[(size_t)r * 32 + i * 8 + j];

    const float4* Q4 = (const float4*)Q;
    const float INV_T = 1.0f / 0.07f;

    for (int i0 = 0; i0 < cnt; i0 += 8) {
        int  i   = i0 + g;
        bool act = (i < cnt);
        unsigned rec = list[bs + (act ? i : 0)];
        int n     = rec & 255;
        int p     = (rec >> 8) & 0x1FFF;
        int isPos = (rec >> 30) & 1;
        int br    = rec >> 31;

        const float4* q = Q4 + ((size_t)(br * P + p)) * 32;
        float d = 0.f;
        #pragma unroll
        for (int i2 = 0; i2 < 4; ++i2) {
            float4 qv = q[i2 * 8 + j];
            float4 ev = er[i2];
            d += ev.x * qv.x + ev.y * qv.y + ev.z * qv.z + ev.w * qv.w;
        }
        d += __shfl_xor(d, 1, 64);
        d += __shfl_xor(d, 2, 64);
        d += __shfl_xor(d, 4, 64);
        d *= INV_T;

        if (act && j == 0) {
            if (isPos) lpos[br * P + p] = d;
            else       zbuf[(((size_t)(br * P + p)) << 8) + n] = d;
        }
    }
}

// ---------------------------------------------------------------------------
// logsumexp + loss: one wave per (branch, p).
// ---------------------------------------------------------------------------
__global__ __launch_bounds__(256) void lse_kernel(const float* __restrict__ zbuf,
                                                  const float* __restrict__ lpos,
                                                  double* __restrict__ accum, int P) {
    const int wv   = threadIdx.x >> 6;
    const int lane = threadIdx.x & 63;
    const int m    = blockIdx.x * 4 + wv;
    if (m >= 2 * P) return;
    const int br = (m >= P) ? 1 : 0;

    const float4* z4 = (const float4*)(zbuf + ((size_t)m << 8));
    float4 v  = z4[lane];
    float  zp = lpos[m];

    float mx = fmaxf(fmaxf(v.x, v.y), fmaxf(v.z, v.w));
    mx = fmaxf(mx, zp);
    #pragma unroll
    for (int s = 32; s >= 1; s >>= 1) mx = fmaxf(mx, __shfl_xor(mx, s, 64));

    float e = expf(v.x - mx) + expf(v.y - mx) + expf(v.z - mx) + expf(v.w - mx);
    if (lane == 0) e += expf(zp - mx);
    #pragma unroll
    for (int s = 32; s >= 1; s >>= 1) e += __shfl_xor(e, s, 64);

    if (lane == 0) {
        float loss  = mx + logf(e) - zp;
        float scale = (br ? 0.1f : 1.0f) / (float)P;
        atomicAdd(accum, (double)(loss * scale));
    }
}

// ---------------------------------------------------------------------------
__global__ void finalize_kernel(const double* __restrict__ accum,
                                float* __restrict__ out) {
    if (threadIdx.x == 0) out[0] = (float)accum[0];
}

// ---------------------------------------------------------------------------
extern "C" void kernel_launch(void* const* d_in, const int* in_sizes, int n_in,
                              void* d_out, int out_size, void* d_ws, size_t ws_size,
                              hipStream_t stream) {
    const float* embeddings  = (const float*)d_in[0];
    const float* W           = (const float*)d_in[1];
    const float* b           = (const float*)d_in[2];
    const int*   pos_anchor   = (const int*)d_in[3];
    const int*   pos_partner  = (const int*)d_in[4];
    const int*   neg_idx      = (const int*)d_in[5];
    const int*   weak_anchor  = (const int*)d_in[6];
    const int*   weak_partner = (const int*)d_in[7];
    const int*   weak_neg_idx = (const int*)d_in[8];
    float* out = (float*)d_out;

    const int N = in_sizes[0] / DD;        // 100000
    const int P = in_sizes[3];             // 8192
    const int TOT = 2 * P * (NEGS + 1);    // 4,210,688 occurrences
    const int NB  = (N + 255) / 256;       // scan blocks

    // ---- workspace layout (256-B aligned regions) ----
    char* ws = (char*)d_ws;
    size_t off = 0;
    auto alloc = [&](size_t bytes) {
        char* p = ws + off;
        off += (bytes + 255) & ~(size_t)255;
        return p;
    };
    double*   accum  = (double*)  alloc(sizeof(double));
    float*    Wt     = (float*)   alloc((size_t)DD * DD * 4);
    float*    emb    = (float*)   alloc((size_t)N * DD * 4);
    float*    Q      = (float*)   alloc((size_t)2 * P * DD * 4);
    float*    zbuf   = (float*)   alloc((size_t)2 * P * NEGS * 4);
    float*    lpos   = (float*)   alloc((size_t)2 * P * 4);
    unsigned* list   = (unsigned*)alloc((size_t)TOT * 4);
    int*      hist   = (int*)     alloc((size_t)N * 4);
    int*      basea  = (int*)     alloc((size_t)N * 4);
    int*      cursor = (int*)     alloc((size_t)N * 4);
    int*      bsum   = (int*)     alloc((size_t)NB * 4);
    int*      bofs   = (int*)     alloc((size_t)NB * 4);
    (void)ws_size;

    init_kernel<<<NB, 256, 0, stream>>>(accum, hist, cursor, N);
    transpose_W<<<DD * DD / 256, 256, 0, stream>>>(W, Wt);

    linear_kernel<<<(N + LTILE - 1) / LTILE, 256, 0, stream>>>(embeddings, Wt, b, emb, N);

    build_q<<<(2 * P + 31) / 32, 256, 0, stream>>>(emb, pos_anchor, weak_anchor, Q, P);

    hist_kernel<<<(TOT + 255) / 256, 256, 0, stream>>>(neg_idx, pos_partner,
                                                       weak_neg_idx, weak_partner,
                                                       hist, P);
    scan1<<<NB, 256, 0, stream>>>(hist, bsum, N);
    scan2<<<1, 64, 0, stream>>>(bsum, bofs, NB);
    scan3<<<NB, 256, 0, stream>>>(hist, bofs, basea, N);

    scatter_kernel<<<(TOT + 255) / 256, 256, 0, stream>>>(neg_idx, pos_partner,
                                                          weak_neg_idx, weak_partner,
                                                          basea, cursor, list, P);

    gather_dot<<<(N + 3) / 4, 256, 0, stream>>>(emb, Q, list, hist, basea,
                                                zbuf, lpos, N, P);

    lse_kernel<<<(2 * P + 3) / 4, 256, 0, stream>>>(zbuf, lpos, accum, P);

    finalize_kernel<<<1, 64, 0, stream>>>(accum, out);
}

// Round 6
// 449.679 us; speedup vs baseline: 2.4233x; 2.4233x over previous
//
#include <hip/hip_runtime.h>
#include <cmath>

#define DD 128          // embedding dim
#define NEGS 256        // negatives per anchor
#define LTILE 64        // rows per linear block

// Journal: R5 row-sorted design FAILED (1090us) — scatter write-amplification
// (4-B random writes -> 257 MB HBM writes, 324us alone). Reverted to R3
// structure. R3 ntxent was latency/concurrency-bound (3.2 TB/s HBM portion,
// VGPR 36, ~4 loads in flight/wave) -> this round: 2-way pipelined gather.

// ---------------------------------------------------------------------------
__global__ void zero_kernel(double* accum) {
    if (threadIdx.x == 0) accum[0] = 0.0;
}

// ---------------------------------------------------------------------------
// Wt[k][c] = W[c][k]
// ---------------------------------------------------------------------------
__global__ __launch_bounds__(256) void transpose_W(const float* __restrict__ W,
                                                   float* __restrict__ Wt) {
    int e = blockIdx.x * 256 + threadIdx.x;
    int c = e >> 7;
    int k = e & 127;
    Wt[k * DD + c] = W[e];
}

// ---------------------------------------------------------------------------
// emb = X @ W.T + b  (fp32 vector ALU).
// 256 thr: cg = t&15 -> 8 cols, rg = t>>4 -> 4 rows. Tile 64 rows.
// X tile in padded LDS (stride 132 floats -> b128 reads conflict-free).
// W loads batched 8-wide per k-chunk for latency hiding.
// ---------------------------------------------------------------------------
__global__ __launch_bounds__(256) void linear_kernel(const float* __restrict__ X,
                                                     const float* __restrict__ Wt,
                                                     const float* __restrict__ b,
                                                     float* __restrict__ Y,
                                                     int N) {
    __shared__ __align__(16) float xs[LTILE][132];   // +4 pad: rows 528 B apart

    const int t  = threadIdx.x;
    const int cg = t & 15;   // cols cg*8 .. cg*8+7
    const int rg = t >> 4;   // rows rg*4 .. rg*4+3
    const int r0 = blockIdx.x * LTILE;

    // stage X tile (coalesced float4 in, padded rows out)
    const float4* X4 = (const float4*)X;
    #pragma unroll
    for (int i = 0; i < 8; ++i) {
        int q   = i * 256 + t;            // 0..2047
        int row = q >> 5;
        int c4  = q & 31;
        float4 v = make_float4(0.f, 0.f, 0.f, 0.f);
        if (r0 + row < N) v = X4[(size_t)(r0 + row) * 32 + c4];
        *((float4*)&xs[row][c4 * 4]) = v;
    }

    const float4* b4 = (const float4*)b;
    float4 b0 = b4[cg * 2], b1 = b4[cg * 2 + 1];
    float acc[4][8];
    #pragma unroll
    for (int j = 0; j < 4; ++j) {
        acc[j][0] = b0.x; acc[j][1] = b0.y; acc[j][2] = b0.z; acc[j][3] = b0.w;
        acc[j][4] = b1.x; acc[j][5] = b1.y; acc[j][6] = b1.z; acc[j][7] = b1.w;
    }
    __syncthreads();

    const float4* Wt4 = (const float4*)Wt;
    #pragma unroll 2
    for (int kc = 0; kc < DD / 4; ++kc) {
        float4 xv[4];
        #pragma unroll
        for (int j = 0; j < 4; ++j)
            xv[j] = *((const float4*)&xs[rg * 4 + j][kc * 4]);
        float4 w0[4], w1[4];
        #pragma unroll
        for (int kk = 0; kk < 4; ++kk) {
            w0[kk] = Wt4[(size_t)(kc * 4 + kk) * 32 + cg * 2];
            w1[kk] = Wt4[(size_t)(kc * 4 + kk) * 32 + cg * 2 + 1];
        }
        #pragma unroll
        for (int kk = 0; kk < 4; ++kk) {
            #pragma unroll
            for (int j = 0; j < 4; ++j) {
                float xk = (kk == 0) ? xv[j].x : (kk == 1) ? xv[j].y
                         : (kk == 2) ? xv[j].z : xv[j].w;
                acc[j][0] += xk * w0[kk].x;
                acc[j][1] += xk * w0[kk].y;
                acc[j][2] += xk * w0[kk].z;
                acc[j][3] += xk * w0[kk].w;
                acc[j][4] += xk * w1[kk].x;
                acc[j][5] += xk * w1[kk].y;
                acc[j][6] += xk * w1[kk].z;
                acc[j][7] += xk * w1[kk].w;
            }
        }
    }

    float4* Y4 = (float4*)Y;
    #pragma unroll
    for (int j = 0; j < 4; ++j) {
        int row = r0 + rg * 4 + j;
        if (row < N) {
            Y4[(size_t)row * 32 + cg * 2]     = make_float4(acc[j][0], acc[j][1], acc[j][2], acc[j][3]);
            Y4[(size_t)row * 32 + cg * 2 + 1] = make_float4(acc[j][4], acc[j][5], acc[j][6], acc[j][7]);
        }
    }
}

// ---------------------------------------------------------------------------
// One block per (branch, p). 256 threads = 4 waves; each wave owns 64 negs.
// Cooperative gather: 8 lanes per row, PF=2 software pipeline -> 8
// independent float4 loads in flight per lane before any consumption
// (2x the in-flight bytes of R3; attacks the Little's-law limit).
// ---------------------------------------------------------------------------
__global__ __launch_bounds__(256) void ntxent_kernel(
        const float* __restrict__ emb,
        const int* __restrict__ anchor0, const int* __restrict__ partner0,
        const int* __restrict__ negidx0,
        const int* __restrict__ anchor1, const int* __restrict__ partner1,
        const int* __restrict__ negidx1,
        double* __restrict__ accum, int P) {
    const int bp     = blockIdx.x;
    const int branch = (bp >= P) ? 1 : 0;
    const int p      = branch ? (bp - P) : bp;

    const int* anchor  = branch ? anchor1  : anchor0;
    const int* partner = branch ? partner1 : partner0;
    const int* negidx  = branch ? negidx1  : negidx0;
    const float scale  = (branch ? 0.1f : 1.0f) / (float)P;
    const float INV_T  = 1.0f / 0.07f;

    __shared__ float4 qs[32];
    __shared__ float  sh_lpos;
    __shared__ float  wred[4];
    __shared__ float  wsum[4];

    const int t    = threadIdx.x;
    const int wave = t >> 6;
    const int lane = t & 63;
    const int grp  = lane >> 3;   // 8 groups of 8 lanes
    const int j    = lane & 7;

    const float4* emb4 = (const float4*)emb;

    const int aidx = anchor[p];
    const int kidx = partner[p];

    if (t < 32) qs[t] = emb4[(size_t)aidx * 32 + t];
    __syncthreads();

    // ---- l_pos on wave 0 ----
    if (t < 64) {
        float part = 0.f;
        if (t < 32) {
            float4 qv = qs[t];
            float4 kv = emb4[(size_t)kidx * 32 + t];
            part = qv.x * kv.x + qv.y * kv.y + qv.z * kv.z + qv.w * kv.w;
        }
        #pragma unroll
        for (int m = 32; m >= 1; m >>= 1) part += __shfl_xor(part, m, 64);
        if (t == 0) sh_lpos = part;
    }

    // ---- q fragments for this lane: float4 slots {j, 8+j, 16+j, 24+j} ----
    float4 qf[4];
    #pragma unroll
    for (int i = 0; i < 4; ++i) qf[i] = qs[i * 8 + j];

    // ---- negative dots: wave's 64 indices loaded coalesced, shfl-dist ----
    const int nbase   = wave * 64;
    const int idx_own = negidx[(size_t)p * NEGS + nbase + lane];

    float zreg[8];
    #pragma unroll
    for (int pi = 0; pi < 8; pi += 2) {
        int nidxA = __shfl(idx_own, pi * 8 + grp, 64);
        int nidxB = __shfl(idx_own, (pi + 1) * 8 + grp, 64);
        const float4* rowA = emb4 + (size_t)nidxA * 32;
        const float4* rowB = emb4 + (size_t)nidxB * 32;

        float4 ra[4], rb[4];
        #pragma unroll
        for (int i = 0; i < 4; ++i) ra[i] = rowA[i * 8 + j];
        #pragma unroll
        for (int i = 0; i < 4; ++i) rb[i] = rowB[i * 8 + j];

        float dA = 0.f, dB = 0.f;
        #pragma unroll
        for (int i = 0; i < 4; ++i) {
            float4 qv = qf[i];
            dA += qv.x * ra[i].x + qv.y * ra[i].y + qv.z * ra[i].z + qv.w * ra[i].w;
            dB += qv.x * rb[i].x + qv.y * rb[i].y + qv.z * rb[i].z + qv.w * rb[i].w;
        }
        dA += __shfl_xor(dA, 1, 64);
        dA += __shfl_xor(dA, 2, 64);
        dA += __shfl_xor(dA, 4, 64);
        dB += __shfl_xor(dB, 1, 64);
        dB += __shfl_xor(dB, 2, 64);
        dB += __shfl_xor(dB, 4, 64);
        zreg[pi]     = dA * INV_T;
        zreg[pi + 1] = dB * INV_T;
    }

    __syncthreads();   // sh_lpos visible
    const float zpos = sh_lpos * INV_T;

    // ---- block max over 257 logits (replication harmless for max) ----
    float m = zreg[0];
    #pragma unroll
    for (int pi = 1; pi < 8; ++pi) m = fmaxf(m, zreg[pi]);
    if (t == 0) m = fmaxf(m, zpos);
    #pragma unroll
    for (int s = 32; s >= 1; s >>= 1) m = fmaxf(m, __shfl_xor(m, s, 64));
    if (lane == 0) wred[wave] = m;
    __syncthreads();
    m = fmaxf(fmaxf(wred[0], wred[1]), fmaxf(wred[2], wred[3]));

    // ---- block sum of exp (only j==0 lanes contribute, kills replication) --
    float e = 0.f;
    if (j == 0) {
        #pragma unroll
        for (int pi = 0; pi < 8; ++pi) e += expf(zreg[pi] - m);
    }
    if (t == 0) e += expf(zpos - m);
    #pragma unroll
    for (int s = 32; s >= 1; s >>= 1) e += __shfl_xor(e, s, 64);
    if (lane == 0) wsum[wave] = e;
    __syncthreads();

    if (t == 0) {
        float S    = wsum[0] + wsum[1] + wsum[2] + wsum[3];
        float loss = m + logf(S) - zpos;
        atomicAdd(accum, (double)(loss * scale));
    }
}

// ---------------------------------------------------------------------------
__global__ void finalize_kernel(const double* __restrict__ accum,
                                float* __restrict__ out) {
    if (threadIdx.x == 0) out[0] = (float)accum[0];
}

// ---------------------------------------------------------------------------
extern "C" void kernel_launch(void* const* d_in, const int* in_sizes, int n_in,
                              void* d_out, int out_size, void* d_ws, size_t ws_size,
                              hipStream_t stream) {
    const float* embeddings  = (const float*)d_in[0];
    const float* W           = (const float*)d_in[1];
    const float* b           = (const float*)d_in[2];
    const int*   pos_anchor   = (const int*)d_in[3];
    const int*   pos_partner  = (const int*)d_in[4];
    const int*   neg_idx      = (const int*)d_in[5];
    const int*   weak_anchor  = (const int*)d_in[6];
    const int*   weak_partner = (const int*)d_in[7];
    const int*   weak_neg_idx = (const int*)d_in[8];
    float* out = (float*)d_out;

    const int N = in_sizes[0] / DD;        // 100000
    const int P = in_sizes[3];             // 8192

    char*   ws    = (char*)d_ws;
    double* accum = (double*)ws;
    float*  Wt    = (float*)(ws + 256);
    float*  emb   = (float*)(ws + 256 + DD * DD * sizeof(float));

    zero_kernel<<<1, 64, 0, stream>>>(accum);
    transpose_W<<<DD * DD / 256, 256, 0, stream>>>(W, Wt);

    linear_kernel<<<(N + LTILE - 1) / LTILE, 256, 0, stream>>>(embeddings, Wt, b, emb, N);

    ntxent_kernel<<<2 * P, 256, 0, stream>>>(emb,
                                             pos_anchor, pos_partner, neg_idx,
                                             weak_anchor, weak_partner, weak_neg_idx,
                                             accum, P);

    finalize_kernel<<<1, 64, 0, stream>>>(accum, out);
}

// Round 7
// 395.767 us; speedup vs baseline: 2.7534x; 1.1362x over previous
//
#include <hip/hip_runtime.h>
#include <hip/hip_fp16.h>
#include <cmath>

#define DD 128          // embedding dim
#define NEGS 256        // negatives per anchor
#define LTILE 64        // rows per linear block

// Journal:
//  R3: thread-owns-row gather 410us -> coop 8-lane gather 310us. FETCH ~1GB.
//  R5: row-sorted redesign FAILED (scatter write-amp 257MB -> 1090us total).
//  R6: PF=2 pipeline: ntxent IDENTICAL 310us @ 46% occ (was 64%) -> fabric
//      throughput ceiling ~6.9 TB/s delivered for random 512B gathers, not
//      latency. Only fewer bytes help => fp16 negative table (this round).

// ---------------------------------------------------------------------------
__global__ void zero_kernel(double* accum) {
    if (threadIdx.x == 0) accum[0] = 0.0;
}

// ---------------------------------------------------------------------------
// Wt[k][c] = W[c][k]
// ---------------------------------------------------------------------------
__global__ __launch_bounds__(256) void transpose_W(const float* __restrict__ W,
                                                   float* __restrict__ Wt) {
    int e = blockIdx.x * 256 + threadIdx.x;
    int c = e >> 7;
    int k = e & 127;
    Wt[k * DD + c] = W[e];
}

// ---------------------------------------------------------------------------
// emb = X @ W.T + b  (fp32 vector ALU), plus fp16 shadow copy for the
// gather-heavy negative dots. W chunk loads double-buffered (A/B named regs,
// all static indices) so L2 latency hides under the FMA block.
// ---------------------------------------------------------------------------
union H2U { __half2 h; unsigned u; };

__global__ __launch_bounds__(256) void linear_kernel(const float* __restrict__ X,
                                                     const float* __restrict__ Wt,
                                                     const float* __restrict__ b,
                                                     float* __restrict__ Y,
                                                     __half* __restrict__ Yh,
                                                     int N) {
    __shared__ __align__(16) float xs[LTILE][132];   // +4 pad

    const int t  = threadIdx.x;
    const int cg = t & 15;   // cols cg*8 .. cg*8+7
    const int rg = t >> 4;   // rows rg*4 .. rg*4+3
    const int r0 = blockIdx.x * LTILE;

    // stage X tile (coalesced float4 in, padded rows out)
    const float4* X4 = (const float4*)X;
    #pragma unroll
    for (int i = 0; i < 8; ++i) {
        int q   = i * 256 + t;            // 0..2047
        int row = q >> 5;
        int c4  = q & 31;
        float4 v = make_float4(0.f, 0.f, 0.f, 0.f);
        if (r0 + row < N) v = X4[(size_t)(r0 + row) * 32 + c4];
        *((float4*)&xs[row][c4 * 4]) = v;
    }

    const float4* b4 = (const float4*)b;
    float4 b0 = b4[cg * 2], b1 = b4[cg * 2 + 1];
    float acc[4][8];
    #pragma unroll
    for (int j = 0; j < 4; ++j) {
        acc[j][0] = b0.x; acc[j][1] = b0.y; acc[j][2] = b0.z; acc[j][3] = b0.w;
        acc[j][4] = b1.x; acc[j][5] = b1.y; acc[j][6] = b1.z; acc[j][7] = b1.w;
    }
    __syncthreads();

    const float4* Wt4 = (const float4*)Wt;

    float4 wA0[4], wA1[4], wB0[4], wB1[4];
    // preload chunk kc=0 into A
    #pragma unroll
    for (int kk = 0; kk < 4; ++kk) {
        wA0[kk] = Wt4[(size_t)kk * 32 + cg * 2];
        wA1[kk] = Wt4[(size_t)kk * 32 + cg * 2 + 1];
    }

    #define FMA_CHUNK(KCBASE, W0, W1)                                        \
        {                                                                    \
            float4 xv[4];                                                    \
            _Pragma("unroll")                                                \
            for (int j = 0; j < 4; ++j)                                      \
                xv[j] = *((const float4*)&xs[rg * 4 + j][(KCBASE) * 4]);     \
            _Pragma("unroll")                                                \
            for (int kk = 0; kk < 4; ++kk) {                                 \
                _Pragma("unroll")                                            \
                for (int j = 0; j < 4; ++j) {                                \
                    float xk = (kk == 0) ? xv[j].x : (kk == 1) ? xv[j].y     \
                             : (kk == 2) ? xv[j].z : xv[j].w;                \
                    acc[j][0] += xk * W0[kk].x;                              \
                    acc[j][1] += xk * W0[kk].y;                              \
                    acc[j][2] += xk * W0[kk].z;                              \
                    acc[j][3] += xk * W0[kk].w;                              \
                    acc[j][4] += xk * W1[kk].x;                              \
                    acc[j][5] += xk * W1[kk].y;                              \
                    acc[j][6] += xk * W1[kk].z;                              \
                    acc[j][7] += xk * W1[kk].w;                              \
                }                                                            \
            }                                                                \
        }

    for (int kc2 = 0; kc2 < 16; ++kc2) {
        const int kcA = 2 * kc2;
        const int kcB = 2 * kc2 + 1;
        // issue B loads before computing A
        #pragma unroll
        for (int kk = 0; kk < 4; ++kk) {
            wB0[kk] = Wt4[(size_t)(kcB * 4 + kk) * 32 + cg * 2];
            wB1[kk] = Wt4[(size_t)(kcB * 4 + kk) * 32 + cg * 2 + 1];
        }
        FMA_CHUNK(kcA, wA0, wA1)
        // issue next A loads before computing B
        if (kc2 < 15) {
            #pragma unroll
            for (int kk = 0; kk < 4; ++kk) {
                wA0[kk] = Wt4[(size_t)((kcA + 2) * 4 + kk) * 32 + cg * 2];
                wA1[kk] = Wt4[(size_t)((kcA + 2) * 4 + kk) * 32 + cg * 2 + 1];
            }
        }
        FMA_CHUNK(kcB, wB0, wB1)
    }
    #undef FMA_CHUNK

    float4* Y4  = (float4*)Y;
    uint4*  Yh4 = (uint4*)Yh;
    #pragma unroll
    for (int j = 0; j < 4; ++j) {
        int row = r0 + rg * 4 + j;
        if (row < N) {
            Y4[(size_t)row * 32 + cg * 2]     = make_float4(acc[j][0], acc[j][1], acc[j][2], acc[j][3]);
            Y4[(size_t)row * 32 + cg * 2 + 1] = make_float4(acc[j][4], acc[j][5], acc[j][6], acc[j][7]);
            H2U h0, h1, h2, h3;
            h0.h = __floats2half2_rn(acc[j][0], acc[j][1]);
            h1.h = __floats2half2_rn(acc[j][2], acc[j][3]);
            h2.h = __floats2half2_rn(acc[j][4], acc[j][5]);
            h3.h = __floats2half2_rn(acc[j][6], acc[j][7]);
            uint4 o; o.x = h0.u; o.y = h1.u; o.z = h2.u; o.w = h3.u;
            Yh4[(size_t)row * 16 + cg] = o;   // row = 16 uint4 chunks of 8 halves
        }
    }
}

// ---------------------------------------------------------------------------
__device__ inline float2 h2f(unsigned u) {
    union { unsigned u; __half2 h; } c; c.u = u;
    return __half22float2(c.h);
}

// ---------------------------------------------------------------------------
// One block per (branch, p). 4 waves x 64 negs. Cooperative gather from the
// fp16 table: 8 lanes per row; lane j reads uint4 chunks {j, j+8} (halves
// 8j..8j+7 and 64+8j..64+8j+7). PF=2 pipeline. l_pos stays fp32-exact.
// ---------------------------------------------------------------------------
__global__ __launch_bounds__(256) void ntxent_kernel(
        const float* __restrict__ emb,
        const __half* __restrict__ embh,
        const int* __restrict__ anchor0, const int* __restrict__ partner0,
        const int* __restrict__ negidx0,
        const int* __restrict__ anchor1, const int* __restrict__ partner1,
        const int* __restrict__ negidx1,
        double* __restrict__ accum, int P) {
    const int bp     = blockIdx.x;
    const int branch = (bp >= P) ? 1 : 0;
    const int p      = branch ? (bp - P) : bp;

    const int* anchor  = branch ? anchor1  : anchor0;
    const int* partner = branch ? partner1 : partner0;
    const int* negidx  = branch ? negidx1  : negidx0;
    const float scale  = (branch ? 0.1f : 1.0f) / (float)P;
    const float INV_T  = 1.0f / 0.07f;

    __shared__ float4 qs[32];
    __shared__ float  sh_lpos;
    __shared__ float  wred[4];
    __shared__ float  wsum[4];

    const int t    = threadIdx.x;
    const int wave = t >> 6;
    const int lane = t & 63;
    const int grp  = lane >> 3;   // 8 groups of 8 lanes
    const int j    = lane & 7;

    const float4* emb4  = (const float4*)emb;
    const uint4*  embh4 = (const uint4*)embh;

    const int aidx = anchor[p];
    const int kidx = partner[p];

    if (t < 32) qs[t] = emb4[(size_t)aidx * 32 + t];
    __syncthreads();

    // ---- l_pos on wave 0 (fp32 exact) ----
    if (t < 64) {
        float part = 0.f;
        if (t < 32) {
            float4 qv = qs[t];
            float4 kv = emb4[(size_t)kidx * 32 + t];
            part = qv.x * kv.x + qv.y * kv.y + qv.z * kv.z + qv.w * kv.w;
        }
        #pragma unroll
        for (int m = 32; m >= 1; m >>= 1) part += __shfl_xor(part, m, 64);
        if (t == 0) sh_lpos = part;
    }

    // ---- q fragments: elems {8j..8j+7} and {64+8j..64+8j+7} ----
    float qA[8], qB[8];
    {
        float4 s0 = qs[2 * j], s1 = qs[2 * j + 1];
        float4 s2 = qs[16 + 2 * j], s3 = qs[16 + 2 * j + 1];
        qA[0] = s0.x; qA[1] = s0.y; qA[2] = s0.z; qA[3] = s0.w;
        qA[4] = s1.x; qA[5] = s1.y; qA[6] = s1.z; qA[7] = s1.w;
        qB[0] = s2.x; qB[1] = s2.y; qB[2] = s2.z; qB[3] = s2.w;
        qB[4] = s3.x; qB[5] = s3.y; qB[6] = s3.z; qB[7] = s3.w;
    }

    const int idx_own = negidx[(size_t)p * NEGS + wave * 64 + lane];

    #define DOT16(U0, U1, DST)                                               \
        {                                                                    \
            float d_ = 0.f; float2 f_;                                       \
            f_ = h2f(U0.x); d_ += qA[0] * f_.x + qA[1] * f_.y;               \
            f_ = h2f(U0.y); d_ += qA[2] * f_.x + qA[3] * f_.y;               \
            f_ = h2f(U0.z); d_ += qA[4] * f_.x + qA[5] * f_.y;               \
            f_ = h2f(U0.w); d_ += qA[6] * f_.x + qA[7] * f_.y;               \
            f_ = h2f(U1.x); d_ += qB[0] * f_.x + qB[1] * f_.y;               \
            f_ = h2f(U1.y); d_ += qB[2] * f_.x + qB[3] * f_.y;               \
            f_ = h2f(U1.z); d_ += qB[4] * f_.x + qB[5] * f_.y;               \
            f_ = h2f(U1.w); d_ += qB[6] * f_.x + qB[7] * f_.y;               \
            d_ += __shfl_xor(d_, 1, 64);                                     \
            d_ += __shfl_xor(d_, 2, 64);                                     \
            d_ += __shfl_xor(d_, 4, 64);                                     \
            DST = d_ * INV_T;                                                \
        }

    float zreg[8];
    #pragma unroll
    for (int pi = 0; pi < 8; pi += 2) {
        int nA = __shfl(idx_own, pi * 8 + grp, 64);
        int nB = __shfl(idx_own, (pi + 1) * 8 + grp, 64);
        const uint4* rA = embh4 + (size_t)nA * 16;
        const uint4* rB = embh4 + (size_t)nB * 16;
        uint4 a0 = rA[j], a1 = rA[j + 8];
        uint4 b0 = rB[j], b1 = rB[j + 8];
        DOT16(a0, a1, zreg[pi])
        DOT16(b0, b1, zreg[pi + 1])
    }
    #undef DOT16

    __syncthreads();   // sh_lpos visible
    const float zpos = sh_lpos * INV_T;

    // ---- block max over 257 logits (replication harmless for max) ----
    float m = zreg[0];
    #pragma unroll
    for (int pi = 1; pi < 8; ++pi) m = fmaxf(m, zreg[pi]);
    if (t == 0) m = fmaxf(m, zpos);
    #pragma unroll
    for (int s = 32; s >= 1; s >>= 1) m = fmaxf(m, __shfl_xor(m, s, 64));
    if (lane == 0) wred[wave] = m;
    __syncthreads();
    m = fmaxf(fmaxf(wred[0], wred[1]), fmaxf(wred[2], wred[3]));

    // ---- block sum of exp (only j==0 lanes contribute) ----
    float e = 0.f;
    if (j == 0) {
        #pragma unroll
        for (int pi = 0; pi < 8; ++pi) e += expf(zreg[pi] - m);
    }
    if (t == 0) e += expf(zpos - m);
    #pragma unroll
    for (int s = 32; s >= 1; s >>= 1) e += __shfl_xor(e, s, 64);
    if (lane == 0) wsum[wave] = e;
    __syncthreads();

    if (t == 0) {
        float S    = wsum[0] + wsum[1] + wsum[2] + wsum[3];
        float loss = m + logf(S) - zpos;
        atomicAdd(accum, (double)(loss * scale));
    }
}

// ---------------------------------------------------------------------------
__global__ void finalize_kernel(const double* __restrict__ accum,
                                float* __restrict__ out) {
    if (threadIdx.x == 0) out[0] = (float)accum[0];
}

// ---------------------------------------------------------------------------
extern "C" void kernel_launch(void* const* d_in, const int* in_sizes, int n_in,
                              void* d_out, int out_size, void* d_ws, size_t ws_size,
                              hipStream_t stream) {
    const float* embeddings  = (const float*)d_in[0];
    const float* W           = (const float*)d_in[1];
    const float* b           = (const float*)d_in[2];
    const int*   pos_anchor   = (const int*)d_in[3];
    const int*   pos_partner  = (const int*)d_in[4];
    const int*   neg_idx      = (const int*)d_in[5];
    const int*   weak_anchor  = (const int*)d_in[6];
    const int*   weak_partner = (const int*)d_in[7];
    const int*   weak_neg_idx = (const int*)d_in[8];
    float* out = (float*)d_out;

    const int N = in_sizes[0] / DD;        // 100000
    const int P = in_sizes[3];             // 8192

    char* ws = (char*)d_ws;
    size_t off = 0;
    auto alloc = [&](size_t bytes) {
        char* p = ws + off;
        off += (bytes + 255) & ~(size_t)255;
        return p;
    };
    double* accum = (double*)alloc(sizeof(double));
    float*  Wt    = (float*) alloc((size_t)DD * DD * 4);
    float*  emb   = (float*) alloc((size_t)N * DD * 4);
    __half* embh  = (__half*)alloc((size_t)N * DD * 2);
    (void)ws_size;

    zero_kernel<<<1, 64, 0, stream>>>(accum);
    transpose_W<<<DD * DD / 256, 256, 0, stream>>>(W, Wt);

    linear_kernel<<<(N + LTILE - 1) / LTILE, 256, 0, stream>>>(embeddings, Wt, b,
                                                               emb, embh, N);

    ntxent_kernel<<<2 * P, 256, 0, stream>>>(emb, embh,
                                             pos_anchor, pos_partner, neg_idx,
                                             weak_anchor, weak_partner, weak_neg_idx,
                                             accum, P);

    finalize_kernel<<<1, 64, 0, stream>>>(accum, out);
}

// Round 9
// 336.836 us; speedup vs baseline: 3.2351x; 1.1750x over previous
//
#include <hip/hip_runtime.h>
#include <hip/hip_fp16.h>
#include <cmath>

#define DD 128          // embedding dim
#define NEGS 256        // negatives per anchor
#define LTILE 64        // rows per linear block
#define TBITS 13        // tile = 8192 rows (2 MB fp16) -> L2-resident
#define TROWS (1 << TBITS)

// Journal:
//  R3: coop 8-lane gather 310us (FETCH ~1GB). R5: sort FAILED (write-amp).
//  R6: PF=2 no change -> throughput ceiling, not latency.
//  R7: fp16 table: 228us, FETCH 460MB for a 25.6MB table => L2/L3 retain
//      little; random 64B lines below L2 run ~2TB/s. HBM/fabric-random bound.
//  R8: persistent 1024 blocks sweep table in 2MB tiles; indices+q in LDS;
//      online LSE in regs. Predict FETCH -> <=100MB, ntxent ~110-150us.
//      (R8 submission hit GPU-acquisition timeout; resubmitted unchanged.)

// ---------------------------------------------------------------------------
__global__ void zero_kernel(double* accum) {
    if (threadIdx.x == 0) accum[0] = 0.0;
}

// ---------------------------------------------------------------------------
__global__ __launch_bounds__(256) void transpose_W(const float* __restrict__ W,
                                                   float* __restrict__ Wt) {
    int e = blockIdx.x * 256 + threadIdx.x;
    int c = e >> 7;
    int k = e & 127;
    Wt[k * DD + c] = W[e];
}

// ---------------------------------------------------------------------------
// emb = X @ W.T + b  (fp32 vector ALU) + fp16 shadow copy. (unchanged R7)
// ---------------------------------------------------------------------------
union H2U { __half2 h; unsigned u; };

__global__ __launch_bounds__(256) void linear_kernel(const float* __restrict__ X,
                                                     const float* __restrict__ Wt,
                                                     const float* __restrict__ b,
                                                     float* __restrict__ Y,
                                                     __half* __restrict__ Yh,
                                                     int N) {
    __shared__ __align__(16) float xs[LTILE][132];   // +4 pad

    const int t  = threadIdx.x;
    const int cg = t & 15;   // cols cg*8 .. cg*8+7
    const int rg = t >> 4;   // rows rg*4 .. rg*4+3
    const int r0 = blockIdx.x * LTILE;

    const float4* X4 = (const float4*)X;
    #pragma unroll
    for (int i = 0; i < 8; ++i) {
        int q   = i * 256 + t;
        int row = q >> 5;
        int c4  = q & 31;
        float4 v = make_float4(0.f, 0.f, 0.f, 0.f);
        if (r0 + row < N) v = X4[(size_t)(r0 + row) * 32 + c4];
        *((float4*)&xs[row][c4 * 4]) = v;
    }

    const float4* b4 = (const float4*)b;
    float4 b0 = b4[cg * 2], b1 = b4[cg * 2 + 1];
    float acc[4][8];
    #pragma unroll
    for (int j = 0; j < 4; ++j) {
        acc[j][0] = b0.x; acc[j][1] = b0.y; acc[j][2] = b0.z; acc[j][3] = b0.w;
        acc[j][4] = b1.x; acc[j][5] = b1.y; acc[j][6] = b1.z; acc[j][7] = b1.w;
    }
    __syncthreads();

    const float4* Wt4 = (const float4*)Wt;

    float4 wA0[4], wA1[4], wB0[4], wB1[4];
    #pragma unroll
    for (int kk = 0; kk < 4; ++kk) {
        wA0[kk] = Wt4[(size_t)kk * 32 + cg * 2];
        wA1[kk] = Wt4[(size_t)kk * 32 + cg * 2 + 1];
    }

    #define FMA_CHUNK(KCBASE, W0, W1)                                        \
        {                                                                    \
            float4 xv[4];                                                    \
            _Pragma("unroll")                                                \
            for (int j = 0; j < 4; ++j)                                      \
                xv[j] = *((const float4*)&xs[rg * 4 + j][(KCBASE) * 4]);     \
            _Pragma("unroll")                                                \
            for (int kk = 0; kk < 4; ++kk) {                                 \
                _Pragma("unroll")                                            \
                for (int j = 0; j < 4; ++j) {                                \
                    float xk = (kk == 0) ? xv[j].x : (kk == 1) ? xv[j].y     \
                             : (kk == 2) ? xv[j].z : xv[j].w;                \
                    acc[j][0] += xk * W0[kk].x;                              \
                    acc[j][1] += xk * W0[kk].y;                              \
                    acc[j][2] += xk * W0[kk].z;                              \
                    acc[j][3] += xk * W0[kk].w;                              \
                    acc[j][4] += xk * W1[kk].x;                              \
                    acc[j][5] += xk * W1[kk].y;                              \
                    acc[j][6] += xk * W1[kk].z;                              \
                    acc[j][7] += xk * W1[kk].w;                              \
                }                                                            \
            }                                                                \
        }

    for (int kc2 = 0; kc2 < 16; ++kc2) {
        const int kcA = 2 * kc2;
        const int kcB = 2 * kc2 + 1;
        #pragma unroll
        for (int kk = 0; kk < 4; ++kk) {
            wB0[kk] = Wt4[(size_t)(kcB * 4 + kk) * 32 + cg * 2];
            wB1[kk] = Wt4[(size_t)(kcB * 4 + kk) * 32 + cg * 2 + 1];
        }
        FMA_CHUNK(kcA, wA0, wA1)
        if (kc2 < 15) {
            #pragma unroll
            for (int kk = 0; kk < 4; ++kk) {
                wA0[kk] = Wt4[(size_t)((kcA + 2) * 4 + kk) * 32 + cg * 2];
                wA1[kk] = Wt4[(size_t)((kcA + 2) * 4 + kk) * 32 + cg * 2 + 1];
            }
        }
        FMA_CHUNK(kcB, wB0, wB1)
    }
    #undef FMA_CHUNK

    float4* Y4  = (float4*)Y;
    uint4*  Yh4 = (uint4*)Yh;
    #pragma unroll
    for (int j = 0; j < 4; ++j) {
        int row = r0 + rg * 4 + j;
        if (row < N) {
            Y4[(size_t)row * 32 + cg * 2]     = make_float4(acc[j][0], acc[j][1], acc[j][2], acc[j][3]);
            Y4[(size_t)row * 32 + cg * 2 + 1] = make_float4(acc[j][4], acc[j][5], acc[j][6], acc[j][7]);
            H2U h0, h1, h2, h3;
            h0.h = __floats2half2_rn(acc[j][0], acc[j][1]);
            h1.h = __floats2half2_rn(acc[j][2], acc[j][3]);
            h2.h = __floats2half2_rn(acc[j][4], acc[j][5]);
            h3.h = __floats2half2_rn(acc[j][6], acc[j][7]);
            uint4 o; o.x = h0.u; o.y = h1.u; o.z = h2.u; o.w = h3.u;
            Yh4[(size_t)row * 16 + cg] = o;
        }
    }
}

// ---------------------------------------------------------------------------
__device__ inline float2 h2f(unsigned u) {
    union { unsigned u; __half2 h; } c; c.u = u;
    return __half22float2(c.h);
}

// ---------------------------------------------------------------------------
// Persistent tile-sweep NT-Xent. Grid = 2P/16 = 1024 blocks (4/CU, all
// co-resident). Block owns 16 pairs m in [bid*16, bid*16+16); wave wv owns
// i4 = 0..3 of them. Table swept in 2MB tiles; matched rows gathered from
// L2-resident tile; per-pair online LSE in registers. l_pos fp32-exact.
// ---------------------------------------------------------------------------
__global__ __launch_bounds__(256) void ntxent_tiled(
        const float* __restrict__ emb,
        const __half* __restrict__ embh,
        const int* __restrict__ anchor0, const int* __restrict__ partner0,
        const int* __restrict__ negidx0,
        const int* __restrict__ anchor1, const int* __restrict__ partner1,
        const int* __restrict__ negidx1,
        double* __restrict__ accum, int P, int ntiles) {
    __shared__ __align__(16) float4 qs4[16 * 32];   // 8 KB: 16 q-rows fp32
    __shared__ int   idxs[16 * 256];                // 16 KB: staged neg indices
    __shared__ int   queue[4][256];                 // 4 KB: per-wave match queue
    __shared__ int   qcnt[4];
    __shared__ float zposl[16];
    __shared__ float lossl[16];

    const int t     = threadIdx.x;
    const int wv    = t >> 6;
    const int lane  = t & 63;
    const int grp   = lane >> 3;
    const int j     = lane & 7;
    const int mbase = blockIdx.x * 16;
    const float INV_T = 1.0f / 0.07f;

    const float4* emb4  = (const float4*)emb;
    const uint4*  embh4 = (const uint4*)embh;

    // ---- stage neg indices: 16 rows x 256, coalesced ----
    #pragma unroll
    for (int i = 0; i < 16; ++i) {
        int m = mbase + i;
        const int* src = (m < P) ? (negidx0 + (size_t)m * NEGS)
                                 : (negidx1 + (size_t)(m - P) * NEGS);
        idxs[i * 256 + t] = src[t];
    }

    // ---- stage q rows (fp32): 8 rows per pass, 32 lanes each ----
    #pragma unroll
    for (int rep = 0; rep < 2; ++rep) {
        int i = rep * 8 + (t >> 5);
        int m = mbase + i;
        int a = (m < P) ? anchor0[m] : anchor1[m - P];
        qs4[i * 32 + (t & 31)] = emb4[(size_t)a * 32 + (t & 31)];
    }
    __syncthreads();

    // ---- l_pos (fp32 exact): dot staged q against partner row ----
    #pragma unroll
    for (int rep = 0; rep < 2; ++rep) {
        int i = rep * 8 + (t >> 5);
        int m = mbase + i;
        int pt = (m < P) ? partner0[m] : partner1[m - P];
        int c  = t & 31;
        float4 kv = emb4[(size_t)pt * 32 + c];
        float4 qv = qs4[i * 32 + c];
        float part = qv.x * kv.x + qv.y * kv.y + qv.z * kv.z + qv.w * kv.w;
        #pragma unroll
        for (int s = 16; s >= 1; s >>= 1) part += __shfl_xor(part, s, 32);
        if (c == 0) zposl[i] = part * INV_T;
    }
    __syncthreads();

    // ---- own indices into registers: 4 pairs x 4 rounds of 64 ----
    int idxr[4][4];
    #pragma unroll
    for (int i4 = 0; i4 < 4; ++i4)
        #pragma unroll
        for (int r = 0; r < 4; ++r)
            idxr[i4][r] = idxs[(wv * 4 + i4) * 256 + r * 64 + lane];

    float ma[4], sa[4];
    #pragma unroll
    for (int i4 = 0; i4 < 4; ++i4) { ma[i4] = -INFINITY; sa[i4] = 0.f; }

    // ---- tile sweep ----
    for (int tile = 0; tile < ntiles; ++tile) {
        #pragma unroll
        for (int i4 = 0; i4 < 4; ++i4) {
            if (lane == 0) qcnt[wv] = 0;
            #pragma unroll
            for (int r = 0; r < 4; ++r) {
                int v = idxr[i4][r];
                if ((v >> TBITS) == tile) {
                    int pos = atomicAdd(&qcnt[wv], 1);
                    queue[wv][pos] = v;
                }
            }
            int cnt = qcnt[wv];
            const int qb = (wv * 4 + i4) * 32;
            for (int g = 0; g < cnt; g += 8) {
                bool act = (g + grp) < cnt;
                int row  = queue[wv][act ? (g + grp) : 0];
                const uint4* rp = embh4 + (size_t)row * 16;
                uint4 u0 = rp[j], u1 = rp[j + 8];
                float4 q0 = qs4[qb + 2 * j],      q1 = qs4[qb + 2 * j + 1];
                float4 q2 = qs4[qb + 16 + 2 * j], q3 = qs4[qb + 17 + 2 * j];
                float d = 0.f; float2 f;
                f = h2f(u0.x); d += q0.x * f.x + q0.y * f.y;
                f = h2f(u0.y); d += q0.z * f.x + q0.w * f.y;
                f = h2f(u0.z); d += q1.x * f.x + q1.y * f.y;
                f = h2f(u0.w); d += q1.z * f.x + q1.w * f.y;
                f = h2f(u1.x); d += q2.x * f.x + q2.y * f.y;
                f = h2f(u1.y); d += q2.z * f.x + q2.w * f.y;
                f = h2f(u1.z); d += q3.x * f.x + q3.y * f.y;
                f = h2f(u1.w); d += q3.z * f.x + q3.w * f.y;
                d += __shfl_xor(d, 1, 64);
                d += __shfl_xor(d, 2, 64);
                d += __shfl_xor(d, 4, 64);
                float z = act ? d * INV_T : -INFINITY;
                float gm = z;
                #pragma unroll
                for (int s = 32; s >= 1; s >>= 1) gm = fmaxf(gm, __shfl_xor(gm, s, 64));
                float mnew = fmaxf(ma[i4], gm);
                float e = (act && j == 0) ? expf(z - mnew) : 0.f;
                #pragma unroll
                for (int s = 32; s >= 1; s >>= 1) e += __shfl_xor(e, s, 64);
                sa[i4] = sa[i4] * expf(ma[i4] - mnew) + e;
                ma[i4] = mnew;
            }
        }
    }

    // ---- finish: fold in l_pos, write per-pair loss ----
    #pragma unroll
    for (int i4 = 0; i4 < 4; ++i4) {
        int m = mbase + wv * 4 + i4;
        float zp = zposl[wv * 4 + i4];
        float mf = fmaxf(ma[i4], zp);
        float sf = sa[i4] * expf(ma[i4] - mf) + expf(zp - mf);
        float loss = mf + logf(sf) - zp;
        float scale = ((m < P) ? 1.0f : 0.1f) / (float)P;
        if (lane == 0) lossl[wv * 4 + i4] = loss * scale;
    }
    __syncthreads();
    if (t == 0) {
        float s = 0.f;
        #pragma unroll
        for (int i = 0; i < 16; ++i) s += lossl[i];
        atomicAdd(accum, (double)s);
    }
}

// ---------------------------------------------------------------------------
__global__ void finalize_kernel(const double* __restrict__ accum,
                                float* __restrict__ out) {
    if (threadIdx.x == 0) out[0] = (float)accum[0];
}

// ---------------------------------------------------------------------------
extern "C" void kernel_launch(void* const* d_in, const int* in_sizes, int n_in,
                              void* d_out, int out_size, void* d_ws, size_t ws_size,
                              hipStream_t stream) {
    const float* embeddings  = (const float*)d_in[0];
    const float* W           = (const float*)d_in[1];
    const float* b           = (const float*)d_in[2];
    const int*   pos_anchor   = (const int*)d_in[3];
    const int*   pos_partner  = (const int*)d_in[4];
    const int*   neg_idx      = (const int*)d_in[5];
    const int*   weak_anchor  = (const int*)d_in[6];
    const int*   weak_partner = (const int*)d_in[7];
    const int*   weak_neg_idx = (const int*)d_in[8];
    float* out = (float*)d_out;

    const int N = in_sizes[0] / DD;        // 100000
    const int P = in_sizes[3];             // 8192
    const int ntiles = (N + TROWS - 1) >> TBITS;

    char* ws = (char*)d_ws;
    size_t off = 0;
    auto alloc = [&](size_t bytes) {
        char* p = ws + off;
        off += (bytes + 255) & ~(size_t)255;
        return p;
    };
    double* accum = (double*)alloc(sizeof(double));
    float*  Wt    = (float*) alloc((size_t)DD * DD * 4);
    float*  emb   = (float*) alloc((size_t)N * DD * 4);
    __half* embh  = (__half*)alloc((size_t)N * DD * 2);
    (void)ws_size;

    zero_kernel<<<1, 64, 0, stream>>>(accum);
    transpose_W<<<DD * DD / 256, 256, 0, stream>>>(W, Wt);

    linear_kernel<<<(N + LTILE - 1) / LTILE, 256, 0, stream>>>(embeddings, Wt, b,
                                                               emb, embh, N);

    ntxent_tiled<<<2 * P / 16, 256, 0, stream>>>(emb, embh,
                                                 pos_anchor, pos_partner, neg_idx,
                                                 weak_anchor, weak_partner, weak_neg_idx,
                                                 accum, P, ntiles);

    finalize_kernel<<<1, 64, 0, stream>>>(accum, out);
}

// Round 10
// 264.531 us; speedup vs baseline: 4.1193x; 1.2733x over previous
//
#include <hip/hip_runtime.h>
#include <hip/hip_fp16.h>
#include <cmath>

#define DD 128          // embedding dim
#define NEGS 256        // negatives per anchor
#define LTILE 64        // rows per linear block
#define TBITS 13        // tile = 8192 rows (2 MB fp16) -> L2-resident
#define TROWS (1 << TBITS)

// Journal:
//  R3: coop 8-lane gather 310us (FETCH ~1GB). R5: sort FAILED (write-amp).
//  R6: PF=2 no change -> throughput ceiling, not latency.
//  R7: fp16 table 228us, FETCH 460MB -> HBM-random bound.
//  R9: tile sweep: FETCH 460->117MB CONFIRMED, but 187us: VALUBusy 58%,
//      occ 44% -> now issue-bound (wave-wide LSE reductions) + occupancy-capped
//      (29KB LDS, 1024 blocks = 4/CU).
//  R10 (this): per-group reg LSE + ballot queue + no idxs LDS (8.3KB) +
//      2048 blocks @ 8/CU. Predict ntxent -> 85-115us, VALUBusy 75-90%.

// ---------------------------------------------------------------------------
__global__ void zero_kernel(double* accum) {
    if (threadIdx.x == 0) accum[0] = 0.0;
}

// ---------------------------------------------------------------------------
__global__ __launch_bounds__(256) void transpose_W(const float* __restrict__ W,
                                                   float* __restrict__ Wt) {
    int e = blockIdx.x * 256 + threadIdx.x;
    int c = e >> 7;
    int k = e & 127;
    Wt[k * DD + c] = W[e];
}

// ---------------------------------------------------------------------------
// emb = X @ W.T + b  (fp32 vector ALU) + fp16 shadow copy. (unchanged R7-R9)
// ---------------------------------------------------------------------------
union H2U { __half2 h; unsigned u; };

__global__ __launch_bounds__(256) void linear_kernel(const float* __restrict__ X,
                                                     const float* __restrict__ Wt,
                                                     const float* __restrict__ b,
                                                     float* __restrict__ Y,
                                                     __half* __restrict__ Yh,
                                                     int N) {
    __shared__ __align__(16) float xs[LTILE][132];   // +4 pad

    const int t  = threadIdx.x;
    const int cg = t & 15;   // cols cg*8 .. cg*8+7
    const int rg = t >> 4;   // rows rg*4 .. rg*4+3
    const int r0 = blockIdx.x * LTILE;

    const float4* X4 = (const float4*)X;
    #pragma unroll
    for (int i = 0; i < 8; ++i) {
        int q   = i * 256 + t;
        int row = q >> 5;
        int c4  = q & 31;
        float4 v = make_float4(0.f, 0.f, 0.f, 0.f);
        if (r0 + row < N) v = X4[(size_t)(r0 + row) * 32 + c4];
        *((float4*)&xs[row][c4 * 4]) = v;
    }

    const float4* b4 = (const float4*)b;
    float4 b0 = b4[cg * 2], b1 = b4[cg * 2 + 1];
    float acc[4][8];
    #pragma unroll
    for (int j = 0; j < 4; ++j) {
        acc[j][0] = b0.x; acc[j][1] = b0.y; acc[j][2] = b0.z; acc[j][3] = b0.w;
        acc[j][4] = b1.x; acc[j][5] = b1.y; acc[j][6] = b1.z; acc[j][7] = b1.w;
    }
    __syncthreads();

    const float4* Wt4 = (const float4*)Wt;

    float4 wA0[4], wA1[4], wB0[4], wB1[4];
    #pragma unroll
    for (int kk = 0; kk < 4; ++kk) {
        wA0[kk] = Wt4[(size_t)kk * 32 + cg * 2];
        wA1[kk] = Wt4[(size_t)kk * 32 + cg * 2 + 1];
    }

    #define FMA_CHUNK(KCBASE, W0, W1)                                        \
        {                                                                    \
            float4 xv[4];                                                    \
            _Pragma("unroll")                                                \
            for (int j = 0; j < 4; ++j)                                      \
                xv[j] = *((const float4*)&xs[rg * 4 + j][(KCBASE) * 4]);     \
            _Pragma("unroll")                                                \
            for (int kk = 0; kk < 4; ++kk) {                                 \
                _Pragma("unroll")                                            \
                for (int j = 0; j < 4; ++j) {                                \
                    float xk = (kk == 0) ? xv[j].x : (kk == 1) ? xv[j].y     \
                             : (kk == 2) ? xv[j].z : xv[j].w;                \
                    acc[j][0] += xk * W0[kk].x;                              \
                    acc[j][1] += xk * W0[kk].y;                              \
                    acc[j][2] += xk * W0[kk].z;                              \
                    acc[j][3] += xk * W0[kk].w;                              \
                    acc[j][4] += xk * W1[kk].x;                              \
                    acc[j][5] += xk * W1[kk].y;                              \
                    acc[j][6] += xk * W1[kk].z;                              \
                    acc[j][7] += xk * W1[kk].w;                              \
                }                                                            \
            }                                                                \
        }

    for (int kc2 = 0; kc2 < 16; ++kc2) {
        const int kcA = 2 * kc2;
        const int kcB = 2 * kc2 + 1;
        #pragma unroll
        for (int kk = 0; kk < 4; ++kk) {
            wB0[kk] = Wt4[(size_t)(kcB * 4 + kk) * 32 + cg * 2];
            wB1[kk] = Wt4[(size_t)(kcB * 4 + kk) * 32 + cg * 2 + 1];
        }
        FMA_CHUNK(kcA, wA0, wA1)
        if (kc2 < 15) {
            #pragma unroll
            for (int kk = 0; kk < 4; ++kk) {
                wA0[kk] = Wt4[(size_t)((kcA + 2) * 4 + kk) * 32 + cg * 2];
                wA1[kk] = Wt4[(size_t)((kcA + 2) * 4 + kk) * 32 + cg * 2 + 1];
            }
        }
        FMA_CHUNK(kcB, wB0, wB1)
    }
    #undef FMA_CHUNK

    float4* Y4  = (float4*)Y;
    uint4*  Yh4 = (uint4*)Yh;
    #pragma unroll
    for (int j = 0; j < 4; ++j) {
        int row = r0 + rg * 4 + j;
        if (row < N) {
            Y4[(size_t)row * 32 + cg * 2]     = make_float4(acc[j][0], acc[j][1], acc[j][2], acc[j][3]);
            Y4[(size_t)row * 32 + cg * 2 + 1] = make_float4(acc[j][4], acc[j][5], acc[j][6], acc[j][7]);
            H2U h0, h1, h2, h3;
            h0.h = __floats2half2_rn(acc[j][0], acc[j][1]);
            h1.h = __floats2half2_rn(acc[j][2], acc[j][3]);
            h2.h = __floats2half2_rn(acc[j][4], acc[j][5]);
            h3.h = __floats2half2_rn(acc[j][6], acc[j][7]);
            uint4 o; o.x = h0.u; o.y = h1.u; o.z = h2.u; o.w = h3.u;
            Yh4[(size_t)row * 16 + cg] = o;
        }
    }
}

// ---------------------------------------------------------------------------
__device__ inline float2 h2f(unsigned u) {
    union { unsigned u; __half2 h; } c; c.u = u;
    return __half22float2(c.h);
}

// ---------------------------------------------------------------------------
// Persistent tile-sweep NT-Xent, v2. Grid = 2P/8 = 2048 blocks (8/CU).
// Block owns 8 pairs; wave wv owns 2 (i4=0,1). Per tile: ballot-built queue,
// 8-lane-group gathers from L2-resident 2MB window, per-group deferred-max
// online LSE in registers (no wave-wide reductions in the hot loop).
// Groups LSE-merged once at the end. l_pos fp32-exact.
// ---------------------------------------------------------------------------
__global__ __launch_bounds__(256, 8) void ntxent_sweep(
        const float* __restrict__ emb,
        const __half* __restrict__ embh,
        const int* __restrict__ anchor0, const int* __restrict__ partner0,
        const int* __restrict__ negidx0,
        const int* __restrict__ anchor1, const int* __restrict__ partner1,
        const int* __restrict__ negidx1,
        double* __restrict__ accum, int P, int ntiles) {
    __shared__ __align__(16) float4 qs4[8 * 32];   // 4 KB: 8 q-rows fp32
    __shared__ int   queue[4][256];                // 4 KB: per-wave match queue
    __shared__ float zposl[8];
    __shared__ float lossl[8];

    const int t     = threadIdx.x;
    const int wv    = t >> 6;
    const int lane  = t & 63;
    const int grp   = lane >> 3;
    const int j     = lane & 7;
    const int mbase = blockIdx.x * 8;
    const float INV_T = 1.0f / 0.07f;

    const float4* emb4  = (const float4*)emb;
    const uint4*  embh4 = (const uint4*)embh;

    // ---- prologue: stage q (own element) + l_pos, no intra-stage barrier ----
    {
        int i = t >> 5, c = t & 31;
        int m  = mbase + i;
        int a  = (m < P) ? anchor0[m]  : anchor1[m - P];
        int pt = (m < P) ? partner0[m] : partner1[m - P];
        float4 qv = emb4[(size_t)a * 32 + c];
        qs4[i * 32 + c] = qv;
        float4 kv = emb4[(size_t)pt * 32 + c];
        float part = qv.x * kv.x + qv.y * kv.y + qv.z * kv.z + qv.w * kv.w;
        #pragma unroll
        for (int s = 16; s >= 1; s >>= 1) part += __shfl_xor(part, s, 32);
        if (c == 0) zposl[i] = part * INV_T;
    }

    // ---- own negative indices -> regs (coalesced, no LDS) ----
    int idxr[2][4];
    #pragma unroll
    for (int i4 = 0; i4 < 2; ++i4) {
        int m = mbase + wv * 2 + i4;
        const int* src = (m < P) ? (negidx0 + (size_t)m * NEGS)
                                 : (negidx1 + (size_t)(m - P) * NEGS);
        #pragma unroll
        for (int r = 0; r < 4; ++r) idxr[i4][r] = src[r * 64 + lane];
    }
    __syncthreads();

    float ms[2], ss[2];
    ms[0] = ms[1] = -1e30f;
    ss[0] = ss[1] = 0.f;

    // ---- tile sweep ----
    for (int tile = 0; tile < ntiles; ++tile) {
        #pragma unroll
        for (int i4 = 0; i4 < 2; ++i4) {
            // ballot-based queue build (wave-uniform cnt, no atomics)
            int cnt = 0;
            #pragma unroll
            for (int r = 0; r < 4; ++r) {
                int v = idxr[i4][r];
                bool match = ((v >> TBITS) == tile);
                unsigned long long mk = __ballot(match);
                if (match)
                    queue[wv][cnt + (int)__popcll(mk & ((1ull << lane) - 1))] = v;
                cnt += (int)__popcll(mk);
            }
            const int qb = (wv * 2 + i4) * 32;
            for (int g = 0; g < cnt; g += 8) {
                bool act = (g + grp) < cnt;
                int row  = queue[wv][act ? (g + grp) : (cnt - 1)];
                const uint4* rp = embh4 + (size_t)row * 16;
                uint4 u0 = rp[j], u1 = rp[j + 8];
                float4 q0 = qs4[qb + 2 * j],      q1 = qs4[qb + 2 * j + 1];
                float4 q2 = qs4[qb + 16 + 2 * j], q3 = qs4[qb + 17 + 2 * j];
                float d = 0.f; float2 f;
                f = h2f(u0.x); d += q0.x * f.x + q0.y * f.y;
                f = h2f(u0.y); d += q0.z * f.x + q0.w * f.y;
                f = h2f(u0.z); d += q1.x * f.x + q1.y * f.y;
                f = h2f(u0.w); d += q1.z * f.x + q1.w * f.y;
                f = h2f(u1.x); d += q2.x * f.x + q2.y * f.y;
                f = h2f(u1.y); d += q2.z * f.x + q2.w * f.y;
                f = h2f(u1.z); d += q3.x * f.x + q3.y * f.y;
                f = h2f(u1.w); d += q3.z * f.x + q3.w * f.y;
                d += __shfl_xor(d, 1, 64);
                d += __shfl_xor(d, 2, 64);
                d += __shfl_xor(d, 4, 64);
                if (act) {
                    float z  = d * INV_T;
                    float mi = ms[i4];
                    if (z <= mi) {
                        ss[i4] += __expf(z - mi);
                    } else {
                        ss[i4] = ss[i4] * __expf(mi - z) + 1.0f;
                        ms[i4] = z;
                    }
                }
            }
        }
    }

    // ---- merge the 8 groups' (m,s), fold l_pos, emit loss ----
    #pragma unroll
    for (int i4 = 0; i4 < 2; ++i4) {
        float m = ms[i4], s = ss[i4];
        #pragma unroll
        for (int off = 8; off <= 32; off <<= 1) {
            float mo = __shfl_xor(m, off, 64);
            float so = __shfl_xor(s, off, 64);
            float mn = fmaxf(m, mo);
            s = s * __expf(m - mn) + so * __expf(mo - mn);
            m = mn;
        }
        int pm = mbase + wv * 2 + i4;
        float zp = zposl[wv * 2 + i4];
        float mf = fmaxf(m, zp);
        float sf = s * __expf(m - mf) + __expf(zp - mf);
        float loss  = mf + logf(sf) - zp;
        float scale = ((pm < P) ? 1.0f : 0.1f) / (float)P;
        if (lane == 0) lossl[wv * 2 + i4] = loss * scale;
    }
    __syncthreads();
    if (t == 0) {
        float s2 = 0.f;
        #pragma unroll
        for (int i = 0; i < 8; ++i) s2 += lossl[i];
        atomicAdd(accum, (double)s2);
    }
}

// ---------------------------------------------------------------------------
__global__ void finalize_kernel(const double* __restrict__ accum,
                                float* __restrict__ out) {
    if (threadIdx.x == 0) out[0] = (float)accum[0];
}

// ---------------------------------------------------------------------------
extern "C" void kernel_launch(void* const* d_in, const int* in_sizes, int n_in,
                              void* d_out, int out_size, void* d_ws, size_t ws_size,
                              hipStream_t stream) {
    const float* embeddings  = (const float*)d_in[0];
    const float* W           = (const float*)d_in[1];
    const float* b           = (const float*)d_in[2];
    const int*   pos_anchor   = (const int*)d_in[3];
    const int*   pos_partner  = (const int*)d_in[4];
    const int*   neg_idx      = (const int*)d_in[5];
    const int*   weak_anchor  = (const int*)d_in[6];
    const int*   weak_partner = (const int*)d_in[7];
    const int*   weak_neg_idx = (const int*)d_in[8];
    float* out = (float*)d_out;

    const int N = in_sizes[0] / DD;        // 100000
    const int P = in_sizes[3];             // 8192
    const int ntiles = (N + TROWS - 1) >> TBITS;

    char* ws = (char*)d_ws;
    size_t off = 0;
    auto alloc = [&](size_t bytes) {
        char* p = ws + off;
        off += (bytes + 255) & ~(size_t)255;
        return p;
    };
    double* accum = (double*)alloc(sizeof(double));
    float*  Wt    = (float*) alloc((size_t)DD * DD * 4);
    float*  emb   = (float*) alloc((size_t)N * DD * 4);
    __half* embh  = (__half*)alloc((size_t)N * DD * 2);
    (void)ws_size;

    zero_kernel<<<1, 64, 0, stream>>>(accum);
    transpose_W<<<DD * DD / 256, 256, 0, stream>>>(W, Wt);

    linear_kernel<<<(N + LTILE - 1) / LTILE, 256, 0, stream>>>(embeddings, Wt, b,
                                                               emb, embh, N);

    ntxent_sweep<<<2 * P / 8, 256, 0, stream>>>(emb, embh,
                                                pos_anchor, pos_partner, neg_idx,
                                                weak_anchor, weak_partner, weak_neg_idx,
                                                accum, P, ntiles);

    finalize_kernel<<<1, 64, 0, stream>>>(accum, out);
}

// Round 11
// 246.164 us; speedup vs baseline: 4.4267x; 1.0746x over previous
//
#include <hip/hip_runtime.h>
#include <hip/hip_fp16.h>
#include <cmath>

#define DD 128          // embedding dim
#define NEGS 256        // negatives per anchor
#define LTILE 64        // rows per linear block
#define TBITS 13        // tile = 8192 rows (2 MB fp16) -> L2-resident
#define TROWS (1 << TBITS)

// Journal:
//  R3: coop 8-lane gather 310us (FETCH ~1GB). R5: sort FAILED (write-amp).
//  R6: PF=2 no change -> fabric throughput ceiling, not latency.
//  R7: fp16 table 228us, FETCH 460MB -> HBM/L3-random bound.
//  R9: tile sweep: FETCH 117MB, 187us -> VALU/occupancy bound.
//  R10: reg-LSE + ballot queue + 8 blocks/CU: 105us, VALUBusy 66%,
//       FETCH 259MB (= 8 XCDs x table x 1.25, structural). Jointly VALU +
//       L3-path bound.
//  R11 (this): v_dot2_f32_f16 dot (8 fdot2 vs 16 cvt+16 fma), q in fp16
//      regs (no hot-loop LDS q reads). Predict sweep -> 72-85us.

// ---------------------------------------------------------------------------
// Wt[k][c] = W[c][k]; thread 0 also zeroes the loss accumulator.
// ---------------------------------------------------------------------------
__global__ __launch_bounds__(256) void transpose_W(const float* __restrict__ W,
                                                   float* __restrict__ Wt,
                                                   double* __restrict__ accum) {
    int e = blockIdx.x * 256 + threadIdx.x;
    if (e == 0) accum[0] = 0.0;
    int c = e >> 7;
    int k = e & 127;
    Wt[k * DD + c] = W[e];
}

// ---------------------------------------------------------------------------
// emb = X @ W.T + b  (fp32 vector ALU) + fp16 shadow copy. (unchanged R7-R10)
// ---------------------------------------------------------------------------
union H2U { __half2 h; unsigned u; };

__global__ __launch_bounds__(256) void linear_kernel(const float* __restrict__ X,
                                                     const float* __restrict__ Wt,
                                                     const float* __restrict__ b,
                                                     float* __restrict__ Y,
                                                     __half* __restrict__ Yh,
                                                     int N) {
    __shared__ __align__(16) float xs[LTILE][132];   // +4 pad

    const int t  = threadIdx.x;
    const int cg = t & 15;   // cols cg*8 .. cg*8+7
    const int rg = t >> 4;   // rows rg*4 .. rg*4+3
    const int r0 = blockIdx.x * LTILE;

    const float4* X4 = (const float4*)X;
    #pragma unroll
    for (int i = 0; i < 8; ++i) {
        int q   = i * 256 + t;
        int row = q >> 5;
        int c4  = q & 31;
        float4 v = make_float4(0.f, 0.f, 0.f, 0.f);
        if (r0 + row < N) v = X4[(size_t)(r0 + row) * 32 + c4];
        *((float4*)&xs[row][c4 * 4]) = v;
    }

    const float4* b4 = (const float4*)b;
    float4 b0 = b4[cg * 2], b1 = b4[cg * 2 + 1];
    float acc[4][8];
    #pragma unroll
    for (int j = 0; j < 4; ++j) {
        acc[j][0] = b0.x; acc[j][1] = b0.y; acc[j][2] = b0.z; acc[j][3] = b0.w;
        acc[j][4] = b1.x; acc[j][5] = b1.y; acc[j][6] = b1.z; acc[j][7] = b1.w;
    }
    __syncthreads();

    const float4* Wt4 = (const float4*)Wt;

    float4 wA0[4], wA1[4], wB0[4], wB1[4];
    #pragma unroll
    for (int kk = 0; kk < 4; ++kk) {
        wA0[kk] = Wt4[(size_t)kk * 32 + cg * 2];
        wA1[kk] = Wt4[(size_t)kk * 32 + cg * 2 + 1];
    }

    #define FMA_CHUNK(KCBASE, W0, W1)                                        \
        {                                                                    \
            float4 xv[4];                                                    \
            _Pragma("unroll")                                                \
            for (int j = 0; j < 4; ++j)                                      \
                xv[j] = *((const float4*)&xs[rg * 4 + j][(KCBASE) * 4]);     \
            _Pragma("unroll")                                                \
            for (int kk = 0; kk < 4; ++kk) {                                 \
                _Pragma("unroll")                                            \
                for (int j = 0; j < 4; ++j) {                                \
                    float xk = (kk == 0) ? xv[j].x : (kk == 1) ? xv[j].y     \
                             : (kk == 2) ? xv[j].z : xv[j].w;                \
                    acc[j][0] += xk * W0[kk].x;                              \
                    acc[j][1] += xk * W0[kk].y;                              \
                    acc[j][2] += xk * W0[kk].z;                              \
                    acc[j][3] += xk * W0[kk].w;                              \
                    acc[j][4] += xk * W1[kk].x;                              \
                    acc[j][5] += xk * W1[kk].y;                              \
                    acc[j][6] += xk * W1[kk].z;                              \
                    acc[j][7] += xk * W1[kk].w;                              \
                }                                                            \
            }                                                                \
        }

    for (int kc2 = 0; kc2 < 16; ++kc2) {
        const int kcA = 2 * kc2;
        const int kcB = 2 * kc2 + 1;
        #pragma unroll
        for (int kk = 0; kk < 4; ++kk) {
            wB0[kk] = Wt4[(size_t)(kcB * 4 + kk) * 32 + cg * 2];
            wB1[kk] = Wt4[(size_t)(kcB * 4 + kk) * 32 + cg * 2 + 1];
        }
        FMA_CHUNK(kcA, wA0, wA1)
        if (kc2 < 15) {
            #pragma unroll
            for (int kk = 0; kk < 4; ++kk) {
                wA0[kk] = Wt4[(size_t)((kcA + 2) * 4 + kk) * 32 + cg * 2];
                wA1[kk] = Wt4[(size_t)((kcA + 2) * 4 + kk) * 32 + cg * 2 + 1];
            }
        }
        FMA_CHUNK(kcB, wB0, wB1)
    }
    #undef FMA_CHUNK

    float4* Y4  = (float4*)Y;
    uint4*  Yh4 = (uint4*)Yh;
    #pragma unroll
    for (int j = 0; j < 4; ++j) {
        int row = r0 + rg * 4 + j;
        if (row < N) {
            Y4[(size_t)row * 32 + cg * 2]     = make_float4(acc[j][0], acc[j][1], acc[j][2], acc[j][3]);
            Y4[(size_t)row * 32 + cg * 2 + 1] = make_float4(acc[j][4], acc[j][5], acc[j][6], acc[j][7]);
            H2U h0, h1, h2, h3;
            h0.h = __floats2half2_rn(acc[j][0], acc[j][1]);
            h1.h = __floats2half2_rn(acc[j][2], acc[j][3]);
            h2.h = __floats2half2_rn(acc[j][4], acc[j][5]);
            h3.h = __floats2half2_rn(acc[j][6], acc[j][7]);
            uint4 o; o.x = h0.u; o.y = h1.u; o.z = h2.u; o.w = h3.u;
            Yh4[(size_t)row * 16 + cg] = o;
        }
    }
}

// ---------------------------------------------------------------------------
typedef _Float16 half2v __attribute__((ext_vector_type(2)));
union U2H { unsigned u; half2v h; };

__device__ inline float2 h2f(unsigned u) {
    union { unsigned u; __half2 h; } c; c.u = u;
    return __half22float2(c.h);
}

__device__ inline float fdot2f(unsigned a, unsigned b, float c) {
#if defined(__has_builtin) && __has_builtin(__builtin_amdgcn_fdot2)
    U2H ua, ub; ua.u = a; ub.u = b;
    return __builtin_amdgcn_fdot2(ua.h, ub.h, c, false);
#else
    float2 fa = h2f(a), fb = h2f(b);
    return c + fa.x * fb.x + fa.y * fb.y;
#endif
}

__device__ inline unsigned packh2(float x, float y) {
    H2U c; c.h = __floats2half2_rn(x, y);
    return c.u;
}

// ---------------------------------------------------------------------------
// Persistent tile-sweep NT-Xent, v3. Grid = 2P/8 = 2048 blocks (8/CU).
// Block owns 8 pairs; wave wv owns 2. Ballot queue; 8-lane-group gathers
// from the L2-resident 2MB window; dot via v_dot2_f32_f16 against fp16 q
// held in REGISTERS (no LDS in the hot loop except the queue broadcast).
// Per-group deferred-max online LSE in regs; merged once at the end.
// l_pos fp32-exact.
// ---------------------------------------------------------------------------
__global__ __launch_bounds__(256, 8) void ntxent_sweep(
        const float* __restrict__ emb,
        const __half* __restrict__ embh,
        const int* __restrict__ anchor0, const int* __restrict__ partner0,
        const int* __restrict__ negidx0,
        const int* __restrict__ anchor1, const int* __restrict__ partner1,
        const int* __restrict__ negidx1,
        double* __restrict__ accum, int P, int ntiles) {
    __shared__ __align__(16) float4 qs4[8 * 32];   // 4 KB: 8 q-rows fp32
    __shared__ int   queue[4][256];                // 4 KB
    __shared__ float zposl[8];
    __shared__ float lossl[8];

    const int t     = threadIdx.x;
    const int wv    = t >> 6;
    const int lane  = t & 63;
    const int grp   = lane >> 3;
    const int j     = lane & 7;
    const int mbase = blockIdx.x * 8;
    const float INV_T = 1.0f / 0.07f;

    const float4* emb4  = (const float4*)emb;
    const uint4*  embh4 = (const uint4*)embh;

    // ---- prologue: stage q (fp32) + l_pos ----
    {
        int i = t >> 5, c = t & 31;
        int m  = mbase + i;
        int a  = (m < P) ? anchor0[m]  : anchor1[m - P];
        int pt = (m < P) ? partner0[m] : partner1[m - P];
        float4 qv = emb4[(size_t)a * 32 + c];
        qs4[i * 32 + c] = qv;
        float4 kv = emb4[(size_t)pt * 32 + c];
        float part = qv.x * kv.x + qv.y * kv.y + qv.z * kv.z + qv.w * kv.w;
        #pragma unroll
        for (int s = 16; s >= 1; s >>= 1) part += __shfl_xor(part, s, 32);
        if (c == 0) zposl[i] = part * INV_T;
    }

    // ---- own negative indices -> regs (coalesced, no LDS) ----
    int idxr[2][4];
    #pragma unroll
    for (int i4 = 0; i4 < 2; ++i4) {
        int m = mbase + wv * 2 + i4;
        const int* src = (m < P) ? (negidx0 + (size_t)m * NEGS)
                                 : (negidx1 + (size_t)(m - P) * NEGS);
        #pragma unroll
        for (int r = 0; r < 4; ++r) idxr[i4][r] = src[r * 64 + lane];
    }
    __syncthreads();

    // ---- q -> fp16 registers (lane's 16 elements per pair) ----
    unsigned qh[2][8];
    #pragma unroll
    for (int i4 = 0; i4 < 2; ++i4) {
        const int qb = (wv * 2 + i4) * 32;
        float4 q0 = qs4[qb + 2 * j],      q1 = qs4[qb + 2 * j + 1];
        float4 q2 = qs4[qb + 16 + 2 * j], q3 = qs4[qb + 17 + 2 * j];
        qh[i4][0] = packh2(q0.x, q0.y); qh[i4][1] = packh2(q0.z, q0.w);
        qh[i4][2] = packh2(q1.x, q1.y); qh[i4][3] = packh2(q1.z, q1.w);
        qh[i4][4] = packh2(q2.x, q2.y); qh[i4][5] = packh2(q2.z, q2.w);
        qh[i4][6] = packh2(q3.x, q3.y); qh[i4][7] = packh2(q3.z, q3.w);
    }

    float ms[2], ss[2];
    ms[0] = ms[1] = -1e30f;
    ss[0] = ss[1] = 0.f;

    // ---- tile sweep ----
    for (int tile = 0; tile < ntiles; ++tile) {
        #pragma unroll
        for (int i4 = 0; i4 < 2; ++i4) {
            // ballot-based queue build
            int cnt = 0;
            #pragma unroll
            for (int r = 0; r < 4; ++r) {
                int v = idxr[i4][r];
                bool match = ((v >> TBITS) == tile);
                unsigned long long mk = __ballot(match);
                if (match)
                    queue[wv][cnt + (int)__popcll(mk & ((1ull << lane) - 1))] = v;
                cnt += (int)__popcll(mk);
            }
            for (int g = 0; g < cnt; g += 8) {
                bool act = (g + grp) < cnt;
                int row  = queue[wv][act ? (g + grp) : (cnt - 1)];
                const uint4* rp = embh4 + (size_t)row * 16;
                uint4 u0 = rp[j], u1 = rp[j + 8];
                float d = 0.f;
                d = fdot2f(qh[i4][0], u0.x, d);
                d = fdot2f(qh[i4][1], u0.y, d);
                d = fdot2f(qh[i4][2], u0.z, d);
                d = fdot2f(qh[i4][3], u0.w, d);
                d = fdot2f(qh[i4][4], u1.x, d);
                d = fdot2f(qh[i4][5], u1.y, d);
                d = fdot2f(qh[i4][6], u1.z, d);
                d = fdot2f(qh[i4][7], u1.w, d);
                d += __shfl_xor(d, 1, 64);
                d += __shfl_xor(d, 2, 64);
                d += __shfl_xor(d, 4, 64);
                if (act) {
                    float z  = d * INV_T;
                    float mi = ms[i4];
                    if (z <= mi) {
                        ss[i4] += __expf(z - mi);
                    } else {
                        ss[i4] = ss[i4] * __expf(mi - z) + 1.0f;
                        ms[i4] = z;
                    }
                }
            }
        }
    }

    // ---- merge the 8 groups' (m,s), fold l_pos, emit loss ----
    #pragma unroll
    for (int i4 = 0; i4 < 2; ++i4) {
        float m = ms[i4], s = ss[i4];
        #pragma unroll
        for (int off = 8; off <= 32; off <<= 1) {
            float mo = __shfl_xor(m, off, 64);
            float so = __shfl_xor(s, off, 64);
            float mn = fmaxf(m, mo);
            s = s * __expf(m - mn) + so * __expf(mo - mn);
            m = mn;
        }
        int pm = mbase + wv * 2 + i4;
        float zp = zposl[wv * 2 + i4];
        float mf = fmaxf(m, zp);
        float sf = s * __expf(m - mf) + __expf(zp - mf);
        float loss  = mf + logf(sf) - zp;
        float scale = ((pm < P) ? 1.0f : 0.1f) / (float)P;
        if (lane == 0) lossl[wv * 2 + i4] = loss * scale;
    }
    __syncthreads();
    if (t == 0) {
        float s2 = 0.f;
        #pragma unroll
        for (int i = 0; i < 8; ++i) s2 += lossl[i];
        atomicAdd(accum, (double)s2);
    }
}

// ---------------------------------------------------------------------------
__global__ void finalize_kernel(const double* __restrict__ accum,
                                float* __restrict__ out) {
    if (threadIdx.x == 0) out[0] = (float)accum[0];
}

// ---------------------------------------------------------------------------
extern "C" void kernel_launch(void* const* d_in, const int* in_sizes, int n_in,
                              void* d_out, int out_size, void* d_ws, size_t ws_size,
                              hipStream_t stream) {
    const float* embeddings  = (const float*)d_in[0];
    const float* W           = (const float*)d_in[1];
    const float* b           = (const float*)d_in[2];
    const int*   pos_anchor   = (const int*)d_in[3];
    const int*   pos_partner  = (const int*)d_in[4];
    const int*   neg_idx      = (const int*)d_in[5];
    const int*   weak_anchor  = (const int*)d_in[6];
    const int*   weak_partner = (const int*)d_in[7];
    const int*   weak_neg_idx = (const int*)d_in[8];
    float* out = (float*)d_out;

    const int N = in_sizes[0] / DD;        // 100000
    const int P = in_sizes[3];             // 8192
    const int ntiles = (N + TROWS - 1) >> TBITS;

    char* ws = (char*)d_ws;
    size_t off = 0;
    auto alloc = [&](size_t bytes) {
        char* p = ws + off;
        off += (bytes + 255) & ~(size_t)255;
        return p;
    };
    double* accum = (double*)alloc(sizeof(double));
    float*  Wt    = (float*) alloc((size_t)DD * DD * 4);
    float*  emb   = (float*) alloc((size_t)N * DD * 4);
    __half* embh  = (__half*)alloc((size_t)N * DD * 2);
    (void)ws_size;

    transpose_W<<<DD * DD / 256, 256, 0, stream>>>(W, Wt, accum);

    linear_kernel<<<(N + LTILE - 1) / LTILE, 256, 0, stream>>>(embeddings, Wt, b,
                                                               emb, embh, N);

    ntxent_sweep<<<2 * P / 8, 256, 0, stream>>>(emb, embh,
                                                pos_anchor, pos_partner, neg_idx,
                                                weak_anchor, weak_partner, weak_neg_idx,
                                                accum, P, ntiles);

    finalize_kernel<<<1, 64, 0, stream>>>(accum, out);
}